// Round 11
// baseline (339.852 us; speedup 1.0000x reference)
//
#include <hip/hip_runtime.h>
#include <hip/hip_bf16.h>

typedef unsigned short u16;
typedef __attribute__((ext_vector_type(4))) float f32x4;
typedef __attribute__((ext_vector_type(4))) unsigned int u32x4;
typedef __attribute__((ext_vector_type(4))) unsigned short u16x4;
typedef __attribute__((ext_vector_type(8))) __bf16 bf16x8;

__device__ inline float u2f(u16 u) {
    union { unsigned int i; float f; } x; x.i = ((unsigned int)u) << 16; return x.f;
}
__device__ inline u16 f2u(float f) {
    __hip_bfloat16 b = __float2bfloat16(f);
    return *reinterpret_cast<u16*>(&b);
}
__device__ inline f32x4 mfma16(bf16x8 a, bf16x8 b, f32x4 c) {
    return __builtin_amdgcn_mfma_f32_16x16x32_bf16(a, b, c, 0, 0, 0);
}
__device__ inline void gload_lds16(const u16* g, u16* l) {
    __builtin_amdgcn_global_load_lds(
        (const __attribute__((address_space(1))) unsigned int*)g,
        (__attribute__((address_space(3))) unsigned int*)l, 16, 0, 0);
}

// ---------------------------------------------------------------------------
// Merged projection GEMMs v2: A-tile persisted in LDS across 4 n-tiles.
// grid (2, 320): y selects {input, weight, bias, out, mode} as before;
// x = n-half. Block stages A[128 m][128 K] once (2 x 64-K buffers), then
// loops 4 n-tiles restaging only B. A logical re-read drops 8x -> 2x.
// ---------------------------------------------------------------------------
__global__ __launch_bounds__(256)
void proj_kernel(const u16* __restrict__ ligb, const u16* __restrict__ protb,
                 const u16* __restrict__ Wl1t, const u16* __restrict__ Wl2t,
                 const u16* __restrict__ Wp1t, const u16* __restrict__ Wp2t,
                 const float* __restrict__ bl1, const float* __restrict__ bl2,
                 const float* __restrict__ bp1, const float* __restrict__ bp2,
                 u16* __restrict__ l1v, u16* __restrict__ l2tv,
                 u16* __restrict__ p1v, u16* __restrict__ p2tv)
{
    __shared__ __align__(16) u16 As[2][128 * 64];
    __shared__ __align__(16) u16 Bs[2][128 * 64];
    const int y = blockIdx.y;
    const u16* A; const u16* B; const float* bias; u16* Out;
    int mode, logL, my;
    if (y < 32)       { A = ligb;  B = Wl1t; bias = bl1; Out = l1v;  mode = 1; logL = 8;  my = y; }
    else if (y < 64)  { A = ligb;  B = Wl2t; bias = bl2; Out = l2tv; mode = 3; logL = 8;  my = y - 32; }
    else if (y < 192) { A = protb; B = Wp1t; bias = bp1; Out = p1v;  mode = 1; logL = 10; my = y - 64; }
    else              { A = protb; B = Wp2t; bias = bp2; Out = p2tv; mode = 3; logL = 10; my = y - 192; }
    const int m0 = my * 128;
    const int nbase = blockIdx.x * 512;
    const int tid = threadIdx.x;
    const int w = tid >> 6, lane = tid & 63, q = lane >> 4, li = lane & 15;
    const int wr = w >> 1, wc = w & 1;

    const int srow = tid >> 3;
    const int cgx = (tid & 7) ^ (srow & 7);
    const int ldsbase = ((tid >> 6) * 8) * 64;

    // stage A (both 64-K halves) once
    #pragma unroll
    for (int h = 0; h < 2; h++) {
        const u16* Ab = A + (long)m0 * 128 + h * 64 + cgx * 8;
        #pragma unroll
        for (int c = 0; c < 4; c++)
            gload_lds16(Ab + (long)(c * 32 + srow) * 128, &As[h][ldsbase + c * 32 * 64]);
    }

    const int Lm = (1 << logL) - 1;
    for (int nt = 0; nt < 4; nt++) {
        const int n0 = nbase + nt * 128;
        #pragma unroll
        for (int h = 0; h < 2; h++) {
            const u16* Bb = B + (long)n0 * 128 + h * 64 + cgx * 8;
            #pragma unroll
            for (int c = 0; c < 4; c++)
                gload_lds16(Bb + (long)(c * 32 + srow) * 128, &Bs[h][ldsbase + c * 32 * 64]);
        }
        __syncthreads();   // staging (A on first iter, B always) complete

        f32x4 acc[4][4];
        #pragma unroll
        for (int i = 0; i < 4; i++)
            #pragma unroll
            for (int j = 0; j < 4; j++) acc[i][j] = (f32x4){0.f, 0.f, 0.f, 0.f};

        #pragma unroll
        for (int h = 0; h < 2; h++) {
            #pragma unroll
            for (int s = 0; s < 2; s++) {
                const int cp = ((s * 4 + q) ^ (li & 7)) * 8;
                bf16x8 av[4], bv[4];
                #pragma unroll
                for (int i = 0; i < 4; i++)
                    av[i] = *(bf16x8*)&As[h][(wr * 64 + i * 16 + li) * 64 + cp];
                #pragma unroll
                for (int j = 0; j < 4; j++)
                    bv[j] = *(bf16x8*)&Bs[h][(wc * 64 + j * 16 + li) * 64 + cp];
                #pragma unroll
                for (int i = 0; i < 4; i++)
                    #pragma unroll
                    for (int j = 0; j < 4; j++)
                        acc[i][j] = mfma16(av[i], bv[j], acc[i][j]);
            }
        }

        #pragma unroll
        for (int i = 0; i < 4; i++) {
            #pragma unroll
            for (int j = 0; j < 4; j++) {
                const int col = n0 + wc * 64 + j * 16 + li;
                const float bvs = bias[col];
                if (mode == 3) {
                    const int row0 = m0 + wr * 64 + i * 16 + q * 4;
                    long base = ((long)(((row0 >> logL) * 8 + (col >> 7)) * 128
                                + (col & 127)) << logL) + (row0 & Lm);
                    u16x4 o;
                    #pragma unroll
                    for (int r = 0; r < 4; r++)
                        o[r] = f2u(fmaxf(acc[i][j][r] + bvs, 0.f));
                    *(u16x4*)(Out + base) = o;
                } else {
                    #pragma unroll
                    for (int r = 0; r < 4; r++) {
                        const int row = m0 + wr * 64 + i * 16 + q * 4 + r;
                        long addr = ((long)((row >> logL) * 8 + (col >> 7)) << (logL + 7))
                                  + ((long)(row & Lm) << 7) + (col & 127);
                        Out[addr] = f2u(fmaxf(acc[i][j][r] + bvs, 0.f));
                    }
                }
            }
        }
        __syncthreads();   // MFMA reads of Bs done before next restage
    }
}

// ---------------------------------------------------------------------------
// Merged AV (unchanged from R10): blocks [0,128) lig AV; [128,640) prot AV
// with conflict-free two-stage transpose.
// ---------------------------------------------------------------------------
__global__ __launch_bounds__(512)
void av_kernel(const u16* __restrict__ att, const u16* __restrict__ p2t,
               const u16* __restrict__ l2t,
               u16* __restrict__ lig3, u16* __restrict__ prot3)
{
    __shared__ __align__(16) u16 As[256 * 64];   // 32 KB
    __shared__ __align__(16) u16 Bs[128 * 64];   // 16 KB
    __shared__ __align__(16) u16 T[64 * 256];    // 32 KB (prot stage-1 tile)
    const int bid = blockIdx.x;
    const int tid = threadIdx.x;
    const int w = tid >> 6, lane = tid & 63, q = lane >> 4, li = lane & 15;
    const int wr = w >> 1, wc = w & 1;

    f32x4 acc[4][4];
    #pragma unroll
    for (int i = 0; i < 4; i++)
        #pragma unroll
        for (int j = 0; j < 4; j++) acc[i][j] = (f32x4){0.f, 0.f, 0.f, 0.f};

    if (bid < 128) {
        const int bh = bid;
        const u16* A = att + (long)bh * 262144;
        const u16* B = p2t + (long)bh * 131072;
        const int srow = tid >> 3;
        const int cg = (tid & 7) ^ (srow & 7);
        const int ldsbase = ((tid >> 6) * 8) * 64;

        for (int kt = 0; kt < 1024; kt += 64) {
            const u16* Ab = A + kt + cg * 8;
            const u16* Bb = B + kt + cg * 8;
            #pragma unroll
            for (int c = 0; c < 4; c++)
                gload_lds16(Ab + (long)(c * 64 + srow) * 1024,
                            &As[ldsbase + c * 64 * 64]);
            #pragma unroll
            for (int c = 0; c < 2; c++)
                gload_lds16(Bb + (long)(c * 64 + srow) * 1024,
                            &Bs[ldsbase + c * 64 * 64]);
            __syncthreads();
            #pragma unroll
            for (int s = 0; s < 2; s++) {
                const int cp = ((s * 4 + q) ^ (li & 7)) * 8;
                bf16x8 av[4], bv[4];
                #pragma unroll
                for (int i = 0; i < 4; i++)
                    av[i] = *(bf16x8*)&As[(wr * 64 + i * 16 + li) * 64 + cp];
                #pragma unroll
                for (int j = 0; j < 4; j++)
                    bv[j] = *(bf16x8*)&Bs[(wc * 64 + j * 16 + li) * 64 + cp];
                #pragma unroll
                for (int i = 0; i < 4; i++)
                    #pragma unroll
                    for (int j = 0; j < 4; j++)
                        acc[i][j] = mfma16(av[i], bv[j], acc[i][j]);
            }
            __syncthreads();
        }

        const long obase = ((long)(bh >> 3) * 256) * 1024 + (long)(bh & 7) * 128;
        #pragma unroll
        for (int i = 0; i < 4; i++)
            #pragma unroll
            for (int j = 0; j < 4; j++) {
                const int col = wc * 64 + j * 16 + li;
                #pragma unroll
                for (int r = 0; r < 4; r++) {
                    const int row = wr * 64 + i * 16 + q * 4 + r;
                    lig3[obase + (long)row * 1024 + col] = f2u(acc[i][j][r]);
                }
            }
    } else {
        const int pb = bid - 128;
        const int bh = pb >> 2;
        const int m0 = (pb & 3) * 256;
        const u16* A = att + (long)bh * 262144;
        const u16* B = l2t + (long)bh * 32768;
        const int w6 = tid >> 6;
        const int i5 = (tid >> 5) & 1;
        const int srow = tid >> 3;
        const int cg = (tid & 7) ^ (srow & 7);
        const int bldsbase = w6 * 8 * 64;

        for (int kt = 0; kt < 256; kt += 64) {
            #pragma unroll
            for (int c = 0; c < 4; c++) {
                gload_lds16(A + (long)(kt + w6 * 8 + c * 2 + i5) * 1024
                              + m0 + (tid & 31) * 8,
                            &T[w6 * 2048 + c * 512]);
            }
            #pragma unroll
            for (int c = 0; c < 2; c++)
                gload_lds16(B + (long)(c * 64 + srow) * 256 + kt + cg * 8,
                            &Bs[bldsbase + c * 64 * 64]);
            __syncthreads();

            #pragma unroll
            for (int pass = 0; pass < 4; pass++) {
                const int p = pass * 64 + (tid & 63);
                union { u16 e[8]; u32x4 v; } tmp;
                #pragma unroll
                for (int e = 0; e < 8; e++)
                    tmp.e[e] = T[(w6 * 8 + e) * 256 + p];
                *(u32x4*)&As[p * 64 + ((w6 ^ (p & 7)) * 8)] = tmp.v;
            }
            __syncthreads();

            #pragma unroll
            for (int s = 0; s < 2; s++) {
                const int cp = ((s * 4 + q) ^ (li & 7)) * 8;
                bf16x8 av[4], bv[4];
                #pragma unroll
                for (int i = 0; i < 4; i++)
                    av[i] = *(bf16x8*)&As[(wr * 64 + i * 16 + li) * 64 + cp];
                #pragma unroll
                for (int j = 0; j < 4; j++)
                    bv[j] = *(bf16x8*)&Bs[(wc * 64 + j * 16 + li) * 64 + cp];
                #pragma unroll
                for (int i = 0; i < 4; i++)
                    #pragma unroll
                    for (int j = 0; j < 4; j++)
                        acc[i][j] = mfma16(av[i], bv[j], acc[i][j]);
            }
            __syncthreads();
        }

        const long obase = ((long)(bh >> 3) * 1024 + m0) * 1024 + (long)(bh & 7) * 128;
        #pragma unroll
        for (int i = 0; i < 4; i++)
            #pragma unroll
            for (int j = 0; j < 4; j++) {
                const int col = wc * 64 + j * 16 + li;
                #pragma unroll
                for (int r = 0; r < 4; r++) {
                    const int row = wr * 64 + i * 16 + q * 4 + r;
                    prot3[obase + (long)row * 1024 + col] = f2u(acc[i][j][r]);
                }
            }
    }
}

// ---------------------------------------------------------------------------
// Merged finals (unchanged from R10)
// ---------------------------------------------------------------------------
__global__ __launch_bounds__(256)
void finals_kernel(const u16* __restrict__ lig3, const u16* __restrict__ ligb,
                   const u16* __restrict__ WstL, const float* __restrict__ bcL,
                   float* __restrict__ out0,
                   const u16* __restrict__ prot3, const u16* __restrict__ protb,
                   const u16* __restrict__ WstP, const float* __restrict__ bcP,
                   float* __restrict__ out1)
{
    __shared__ __align__(16) u16 As[128 * 64];
    __shared__ __align__(16) u16 Bs[128 * 64];
    const int y = blockIdx.y;
    const u16 *A, *A2, *B; const float* bias; float* Out; int my;
    if (y < 32) { A = lig3;  A2 = ligb;  B = WstL; bias = bcL; Out = out0; my = y; }
    else        { A = prot3; A2 = protb; B = WstP; bias = bcP; Out = out1; my = y - 32; }
    const int m0 = my * 128;
    const int tid = threadIdx.x;
    const int w = tid >> 6, lane = tid & 63, q = lane >> 4, li = lane & 15;
    const int wr = w >> 1, wc = w & 1;

    const int srow = tid >> 3;
    const int cg = (tid & 7) ^ (srow & 7);
    const int ldsbase = ((tid >> 6) * 8) * 64;

    f32x4 acc[4][4];
    #pragma unroll
    for (int i = 0; i < 4; i++)
        #pragma unroll
        for (int j = 0; j < 4; j++) acc[i][j] = (f32x4){0.f, 0.f, 0.f, 0.f};

    for (int kt = 0; kt < 1152; kt += 64) {
        const u16* Abase; long lda; int ktA;
        if (kt >= 1024) { Abase = A2; lda = 128; ktA = kt - 1024; }
        else            { Abase = A;  lda = 1024; ktA = kt; }
        const u16* Ab = Abase + (long)m0 * lda + ktA + cg * 8;
        const u16* Bb = B + kt + cg * 8;
        #pragma unroll
        for (int c = 0; c < 4; c++) {
            gload_lds16(Ab + (long)(c * 32 + srow) * lda,  &As[ldsbase + c * 32 * 64]);
            gload_lds16(Bb + (long)(c * 32 + srow) * 1152, &Bs[ldsbase + c * 32 * 64]);
        }
        __syncthreads();
        #pragma unroll
        for (int s = 0; s < 2; s++) {
            const int cp = ((s * 4 + q) ^ (li & 7)) * 8;
            bf16x8 av[4], bv[4];
            #pragma unroll
            for (int i = 0; i < 4; i++)
                av[i] = *(bf16x8*)&As[(wr * 64 + i * 16 + li) * 64 + cp];
            #pragma unroll
            for (int j = 0; j < 4; j++)
                bv[j] = *(bf16x8*)&Bs[(wc * 64 + j * 16 + li) * 64 + cp];
            #pragma unroll
            for (int i = 0; i < 4; i++)
                #pragma unroll
                for (int j = 0; j < 4; j++)
                    acc[i][j] = mfma16(av[i], bv[j], acc[i][j]);
        }
        __syncthreads();
    }

    #pragma unroll
    for (int i = 0; i < 4; i++)
        #pragma unroll
        for (int j = 0; j < 4; j++) {
            const int col = wc * 64 + j * 16 + li;
            const float bvs = bias[col];
            #pragma unroll
            for (int r = 0; r < 4; r++) {
                const int row = m0 + wr * 64 + i * 16 + q * 4 + r;
                Out[(long)row * 128 + col] = fmaxf(acc[i][j][r] + bvs, 0.f);
            }
        }
}

// ---------------------------------------------------------------------------
// Attention v4: m-tile 32, 512 threads = 8 waves (2 row-groups x 4 col-groups).
// Same per-wave structure as the proven v1 (sv[16][4], 64 VGPRs), but each
// block covers 32 l-rows -> p1 logical re-reads halve (8 blocks/bh vs 16).
// grid (8, 128).
// ---------------------------------------------------------------------------
__global__ __launch_bounds__(512)
void attn_kernel(const u16* __restrict__ l1, const u16* __restrict__ p1,
                 const float* __restrict__ inter, u16* __restrict__ att)
{
    __shared__ __align__(16) u16 As[32][136];
    __shared__ float wmax[8][16];
    __shared__ float wsum[8][16];
    const int bh = blockIdx.y;
    const int b  = bh >> 3;
    const int m0 = blockIdx.x * 32;
    const int tid = threadIdx.x;
    const int w = tid >> 6, lane = tid & 63, q = lane >> 4, li = lane & 15;
    const int rg = w >> 2, cg = w & 3;     // row-group 0..1, col-group 0..3

    {
        const int row = tid >> 4, col = (tid & 15) * 8;
        *(u32x4*)&As[row][col] =
            *(const u32x4*)(l1 + ((long)bh * 256 + m0 + row) * 128 + col);
    }
    __syncthreads();

    bf16x8 af[4];
    #pragma unroll
    for (int s = 0; s < 4; s++) af[s] = *(bf16x8*)&As[rg * 16 + li][s * 32 + q * 8];

    float sv[16][4];
    const float rscale = 0.08838834764831845f; // 1/sqrt(128)
    for (int t = 0; t < 16; t++) {
        const int n0 = cg * 256 + t * 16;
        const u16* bp = p1 + ((long)bh * 1024 + n0 + li) * 128 + q * 8;
        f32x4 acc = (f32x4){0.f, 0.f, 0.f, 0.f};
        #pragma unroll
        for (int s = 0; s < 4; s++) {
            bf16x8 bfg = *(const bf16x8*)(bp + s * 32);
            acc = mfma16(af[s], bfg, acc);
        }
        const int pcol = n0 + li;
        #pragma unroll
        for (int r = 0; r < 4; r++) {
            const int l = m0 + rg * 16 + q * 4 + r;
            float iv = inter[((long)b * 256 + l) * 1024 + pcol];
            sv[t][r] = acc[r] * rscale * iv;
        }
    }

    #pragma unroll
    for (int r = 0; r < 4; r++) {
        float m = sv[0][r];
        #pragma unroll
        for (int t = 1; t < 16; t++) m = fmaxf(m, sv[t][r]);
        for (int d = 1; d < 16; d <<= 1) m = fmaxf(m, __shfl_xor(m, d, 64));
        if (li == 0) wmax[w][q * 4 + r] = m;
    }
    __syncthreads();
    float gmax[4];
    #pragma unroll
    for (int r = 0; r < 4; r++) {
        gmax[r] = fmaxf(fmaxf(wmax[rg * 4 + 0][q * 4 + r], wmax[rg * 4 + 1][q * 4 + r]),
                        fmaxf(wmax[rg * 4 + 2][q * 4 + r], wmax[rg * 4 + 3][q * 4 + r]));
    }
    #pragma unroll
    for (int r = 0; r < 4; r++) {
        float s = 0.f;
        #pragma unroll
        for (int t = 0; t < 16; t++) {
            float e = __expf(sv[t][r] - gmax[r]);
            sv[t][r] = e;
            s += e;
        }
        for (int d = 1; d < 16; d <<= 1) s += __shfl_xor(s, d, 64);
        if (li == 0) wsum[w][q * 4 + r] = s;
    }
    __syncthreads();
    float inv[4];
    #pragma unroll
    for (int r = 0; r < 4; r++) {
        float s = wsum[rg * 4 + 0][q * 4 + r] + wsum[rg * 4 + 1][q * 4 + r]
                + wsum[rg * 4 + 2][q * 4 + r] + wsum[rg * 4 + 3][q * 4 + r];
        inv[r] = 1.f / s;
    }
    for (int t = 0; t < 16; t++) {
        #pragma unroll
        for (int r = 0; r < 4; r++) {
            const int l = m0 + rg * 16 + q * 4 + r;
            const int pcol = cg * 256 + t * 16 + li;
            att[((long)bh * 256 + l) * 1024 + pcol] = f2u(sv[t][r] * inv[r]);
        }
    }
}

// ---------------------------------------------------------------------------
// Fused 8-way transpose + fp32->bf16 convert for weights (unchanged)
// ---------------------------------------------------------------------------
struct TPF { const float* src; u16* dst; int R; int C; };
struct TPF8 { TPF t[8]; };

__global__ __launch_bounds__(256)
void cvtw_kernel(TPF8 args)
{
    TPF tp = args.t[blockIdx.z];
    const int c0 = blockIdx.x * 32, r0 = blockIdx.y * 32;
    if (c0 >= tp.C || r0 >= tp.R) return;
    __shared__ u16 tile[32][33];
    const int tx = threadIdx.x & 31, ty = threadIdx.x >> 5;
    #pragma unroll
    for (int i = 0; i < 4; i++)
        tile[ty + i * 8][tx] = f2u(tp.src[(long)(r0 + ty + i * 8) * tp.C + c0 + tx]);
    __syncthreads();
    #pragma unroll
    for (int i = 0; i < 4; i++)
        tp.dst[(long)(c0 + ty + i * 8) * tp.R + r0 + tx] = tile[tx][ty + i * 8];
}

// ---------------------------------------------------------------------------
// Weight-combine (unchanged)
// ---------------------------------------------------------------------------
__global__ __launch_bounds__(256)
void wcomb_kernel(const u16* __restrict__ Wm0, const u16* __restrict__ Wo0,
                  const float* __restrict__ bm0, const float* __restrict__ bo0,
                  u16* __restrict__ Wst0, float* __restrict__ bc0,
                  const u16* __restrict__ Wm1, const u16* __restrict__ Wo1,
                  const float* __restrict__ bm1, const float* __restrict__ bo1,
                  u16* __restrict__ Wst1, float* __restrict__ bc1)
{
    const int zz = blockIdx.y;
    const u16* Wm = zz ? Wm1 : Wm0;
    const u16* Wo = zz ? Wo1 : Wo0;
    const float* bmid = zz ? bm1 : bm0;
    const float* bout = zz ? bo1 : bo0;
    u16* Wst = zz ? Wst1 : Wst0;
    float* bc = zz ? bc1 : bc0;
    const int n = blockIdx.x;
    const int tid = threadIdx.x;
    __shared__ float wrow[128];
    if (tid < 128) wrow[tid] = u2f(Wo[n * 256 + tid]);
    __syncthreads();
    for (int k = tid; k < 1024; k += 256) {
        float acc = 0.f;
        #pragma unroll 4
        for (int j = 0; j < 128; j++) acc += wrow[j] * u2f(Wm[(long)j * 1024 + k]);
        Wst[(long)n * 1152 + k] = f2u(acc);
    }
    if (tid < 128) Wst[(long)n * 1152 + 1024 + tid] = Wo[n * 256 + 128 + tid];
    if (tid == 0) {
        float acc = bout[n];
        for (int j = 0; j < 128; j++) acc += bmid[j] * wrow[j];
        bc[n] = acc;
    }
}

// ---------------------------------------------------------------------------
// fp32 -> bf16 converts: z=0 ligand, z=1 prot (inter stays fp32)
// ---------------------------------------------------------------------------
__global__ __launch_bounds__(256)
void cvt2_kernel(const float* __restrict__ a, u16* __restrict__ da, int na,
                 const float* __restrict__ b, u16* __restrict__ db, int nb)
{
    const int zz = blockIdx.y;
    const float* s = zz ? b : a;
    u16* d = zz ? db : da;
    const int n = zz ? nb : na;
    const int i = (blockIdx.x * 256 + threadIdx.x) * 4;
    if (i >= n) return;
    const float4 v = *(const float4*)(s + i);
    u16x4 o;
    o.x = f2u(v.x); o.y = f2u(v.y); o.z = f2u(v.z); o.w = f2u(v.w);
    *(u16x4*)(d + i) = o;
}

// ---------------------------------------------------------------------------
extern "C" void kernel_launch(void* const* d_in, const int* in_sizes, int n_in,
                              void* d_out, int out_size, void* d_ws, size_t ws_size,
                              hipStream_t stream)
{
    (void)in_sizes; (void)n_in; (void)out_size; (void)ws_size;
    const float* ligand = (const float*)d_in[0];
    const float* prot   = (const float*)d_in[1];
    const float* inter  = (const float*)d_in[2];
    const float* Wl1 = (const float*)d_in[3];  const float* bl1 = (const float*)d_in[4];
    const float* Wl2 = (const float*)d_in[5];  const float* bl2 = (const float*)d_in[6];
    const float* Wp1 = (const float*)d_in[7];  const float* bp1 = (const float*)d_in[8];
    const float* Wp2 = (const float*)d_in[9];  const float* bp2 = (const float*)d_in[10];
    const float* W11 = (const float*)d_in[11]; const float* b11 = (const float*)d_in[12];
    const float* W12 = (const float*)d_in[13]; const float* b12 = (const float*)d_in[14];
    const float* W21 = (const float*)d_in[15]; const float* b21 = (const float*)d_in[16];
    const float* W22 = (const float*)d_in[17]; const float* b22 = (const float*)d_in[18];

    float* out0 = (float*)d_out;                    // [16,256,128]
    float* out1 = out0 + (size_t)16 * 256 * 128;    // [16,1024,128]

    u16* ws = (u16*)d_ws;
    size_t off = 0;
    auto alloc = [&](size_t n) { u16* p = ws + off; off += n; return p; };
    u16* ligb  = alloc(524288);    // bf16 ligand [4096,128]
    u16* protb = alloc(2097152);   // bf16 prot  [16384,128]
    u16* l1v   = alloc(4194304);   // [16,8,256,128]
    u16* l2t   = alloc(4194304);   // [16,8,128,256]  (head-T)
    u16* p1v   = alloc(16777216);  // [16,8,1024,128]
    u16* p2t   = alloc(16777216);  // [16,8,128,1024] (head-T)
    u16* attv  = alloc(33554432);  // [16,8,256,1024]
    u16* lig3  = alloc(4194304);   // [16,256,1024]
    u16* prot3 = alloc(16777216);  // [16,1024,1024]
    u16* Wl1t  = alloc(131072);    // [1024,128]
    u16* Wl2t  = alloc(131072);
    u16* Wp1t  = alloc(131072);
    u16* Wp2t  = alloc(131072);
    u16* W11t  = alloc(131072);    // [128,1024] = W11^T
    u16* W21t  = alloc(131072);    // [128,1024] = W21^T
    u16* W12t  = alloc(32768);     // [128,256]  = W12^T
    u16* W22t  = alloc(32768);     // [128,256]  = W22^T
    u16* WstL  = alloc(147456);    // [128,1152] combined lig weight
    u16* WstP  = alloc(147456);    // [128,1152] combined prot weight
    float* bcL = (float*)alloc(256);  // [128] f32
    float* bcP = (float*)alloc(256);  // [128] f32

    // input conversion (ligand, prot) -> bf16; inter stays fp32
    cvt2_kernel<<<dim3(2048, 2), 256, 0, stream>>>(
        ligand, ligb, 524288, prot, protb, 2097152);

    TPF8 tp;
    tp.t[0] = {Wl1, Wl1t, 128, 1024};
    tp.t[1] = {Wl2, Wl2t, 128, 1024};
    tp.t[2] = {Wp1, Wp1t, 128, 1024};
    tp.t[3] = {Wp2, Wp2t, 128, 1024};
    tp.t[4] = {W11, W11t, 1024, 128};
    tp.t[5] = {W21, W21t, 1024, 128};
    tp.t[6] = {W12, W12t, 256, 128};
    tp.t[7] = {W22, W22t, 256, 128};
    cvtw_kernel<<<dim3(32, 32, 8), 256, 0, stream>>>(tp);

    // combine W11@W12top / W21@W22top + residual halves + biases
    wcomb_kernel<<<dim3(128, 2), 256, 0, stream>>>(
        W11t, W12t, b11, b12, WstL, bcL,
        W21t, W22t, b21, b22, WstP, bcP);

    // all four projections in one dispatch (A-tile persisted, 4 n-tiles/block)
    proj_kernel<<<dim3(2, 320), 256, 0, stream>>>(
        ligb, protb, Wl1t, Wl2t, Wp1t, Wp2t,
        bl1, bl2, bp1, bp2, l1v, l2t, p1v, p2t);

    // attention scores + softmax (m-tile 32, 512 threads)
    attn_kernel<<<dim3(8, 128), 512, 0, stream>>>(l1v, p1v, inter, attv);

    // both AV GEMMs in one dispatch (conflict-free prot transpose staging)
    av_kernel<<<dim3(640), 512, 0, stream>>>(attv, p2t, l2t, lig3, prot3);

    // both fused finals in one dispatch
    finals_kernel<<<dim3(1, 160), 256, 0, stream>>>(
        lig3, ligb, WstL, bcL, out0,
        prot3, protb, WstP, bcP, out1);
}